// Round 16
// baseline (299.326 us; speedup 1.0000x reference)
//
#include <hip/hip_runtime.h>
#include <math.h>

#define D_MODEL 768
#define NUM_HEADS 12
#define D_K 64
#define SEQ 4096
#define BATCH 2
#define BH_ (BATCH*NUM_HEADS)
#define MROWS (BATCH*SEQ)     // 8192

typedef __attribute__((ext_vector_type(8))) short bf16x8;
typedef __attribute__((ext_vector_type(4))) float f32x4;
typedef unsigned short u16;
typedef unsigned int u32;

__device__ __forceinline__ u16 f2bf(float f) {
    union { float f; u32 u; } v; v.f = f;
    u32 r = v.u + 0x7fffu + ((v.u >> 16) & 1u);   // RNE
    return (u16)(r >> 16);
}
__device__ __forceinline__ float fast_exp2(float x) {
#if __has_builtin(__builtin_amdgcn_exp2f)
    return __builtin_amdgcn_exp2f(x);
#else
    return exp2f(x);
#endif
}
// async global->LDS DMA: LDS dest = uniform base + lane*16
__device__ __forceinline__ void gload_lds16(const u16* g, u16* l) {
    __builtin_amdgcn_global_load_lds(
        (const __attribute__((address_space(1))) void*)g,
        (__attribute__((address_space(3))) void*)l, 16, 0, 0);
}
__device__ __forceinline__ f32x4 mfma16(bf16x8 a, bf16x8 b, f32x4 c) {
    return __builtin_amdgcn_mfma_f32_16x16x32_bf16(a, b, c, 0, 0, 0);
}

// ---------------------------------------------------------------------------
// convert x -> Xh (plain bf16, RNE).  8 elements / thread.
// ---------------------------------------------------------------------------
__global__ __launch_bounds__(256)
void convert_x(const float* __restrict__ x, u16* __restrict__ Xh)
{
    int i = (blockIdx.x * 256 + threadIdx.x) * 8;
    float4 a = *(const float4*)&x[i];
    float4 b = *(const float4*)&x[i + 4];
    u16 h0 = f2bf(a.x), h1 = f2bf(a.y), h2 = f2bf(a.z), h3 = f2bf(a.w);
    u16 h4 = f2bf(b.x), h5 = f2bf(b.y), h6 = f2bf(b.z), h7 = f2bf(b.w);
    uint4 H;
    H.x = (u32)h0 | ((u32)h1 << 16); H.y = (u32)h2 | ((u32)h3 << 16);
    H.z = (u32)h4 | ((u32)h5 << 16); H.w = (u32)h6 | ((u32)h7 << 16);
    *(uint4*)&Xh[i] = H;
}

// ---------------------------------------------------------------------------
// convert weights -> plain bf16 h.  z selects Wq/Wk/Wv/Wo.
// ---------------------------------------------------------------------------
__global__ __launch_bounds__(256)
void convert_w(const float* __restrict__ Wq, const float* __restrict__ Wk,
               const float* __restrict__ Wv, const float* __restrict__ Wo,
               u16* __restrict__ Wqh, u16* __restrict__ Wkh,
               u16* __restrict__ Wvh, u16* __restrict__ Woh)
{
    const int z = blockIdx.y;
    const float* __restrict__ src = (z==0)?Wq:(z==1)?Wk:(z==2)?Wv:Wo;
    u16* __restrict__ dh = (z==0)?Wqh:(z==1)?Wkh:(z==2)?Wvh:Woh;

    int i = (blockIdx.x * 256 + threadIdx.x) * 8;
    float4 a = *(const float4*)&src[i];
    float4 b = *(const float4*)&src[i + 4];
    u16 h0 = f2bf(a.x), h1 = f2bf(a.y), h2 = f2bf(a.z), h3 = f2bf(a.w);
    u16 h4 = f2bf(b.x), h5 = f2bf(b.y), h6 = f2bf(b.z), h7 = f2bf(b.w);
    uint4 H;
    H.x = (u32)h0 | ((u32)h1 << 16); H.y = (u32)h2 | ((u32)h3 << 16);
    H.z = (u32)h4 | ((u32)h5 << 16); H.w = (u32)h6 | ((u32)h7 << 16);
    *(uint4*)&dh[i] = H;
}

// ---------------------------------------------------------------------------
// QKV projection, MFMA.  128x128 tile, 4 waves (2x2 of 64x64).
// R16: BK=64 — one barrier pair per 64 K-cols (12 iters vs 24), staged as
// TWO back-to-back [128][32] sub-tiles (kk) so every DMA chunk and fragment
// read keeps the verified BK=32 pattern (64-B rows: no new bank geometry).
// Math order per k unchanged -> bit-identical output (absmax is a control).
// LDS 32 KB -> 5 blocks/CU cap >= 4.5 resident avg: no occupancy loss.
// ---------------------------------------------------------------------------
__global__ __launch_bounds__(256)
void proj_gemm(const u16* __restrict__ Xh,
               const u16* __restrict__ Wqh, const u16* __restrict__ Wkh,
               const u16* __restrict__ Wvh,
               const float* __restrict__ bq, const float* __restrict__ bk,
               const float* __restrict__ bv,
               u16* __restrict__ Qh, u16* __restrict__ Kh, u16* __restrict__ Vh)
{
    const int z = blockIdx.z;
    const u16* __restrict__ Bh_ = (z==0)?Wqh:(z==1)?Wkh:Wvh;
    const float* __restrict__ bias = (z==0)?bq:(z==1)?bk:bv;

    __shared__ __align__(16) u16 sAh[2*128*32];   // kk*4096 + chunk*512
    __shared__ __align__(16) u16 sBh[2*128*32];

    const int tid  = threadIdx.x;
    const int lane = tid & 63;
    const int ln   = lane & 15, quad = lane >> 4;
    const int w    = tid >> 6;
    const int wr   = (w & 1) * 64;
    const int wc   = (w >> 1) * 64;
    const int m0   = blockIdx.x * 128;
    const int n0   = blockIdx.y * 128;

    const int lr = lane >> 2;          // 0..15 row within 16-row chunk
    const int lc = (lane & 3) * 8;     // u16 col (0,8,16,24)

    f32x4 acc[4][4];
    const f32x4 z4 = {0.f,0.f,0.f,0.f};
#pragma unroll
    for (int s = 0; s < 4; ++s)
#pragma unroll
        for (int j = 0; j < 4; ++j) acc[s][j] = z4;

#pragma unroll 1
    for (int k0 = 0; k0 < D_MODEL; k0 += 64) {
        __syncthreads();   // previous tile fully consumed before DMA overwrite
#pragma unroll
        for (int kk = 0; kk < 2; ++kk) {
#pragma unroll
            for (int cc = 0; cc < 2; ++cc) {
                const int c  = w*2 + cc;        // chunk 0..7 (16 rows each)
                const int gr = c*16 + lr;
                gload_lds16(&Xh [(size_t)(m0 + gr)*D_MODEL + k0 + kk*32 + lc],
                            &sAh[kk*4096 + c*512]);
                gload_lds16(&Bh_[(size_t)(n0 + gr)*D_MODEL + k0 + kk*32 + lc],
                            &sBh[kk*4096 + c*512]);
            }
        }
        __syncthreads();   // drains vmcnt -> DMA data visible

#pragma unroll
        for (int kk = 0; kk < 2; ++kk) {
            bf16x8 a_h[4];
#pragma unroll
            for (int s = 0; s < 4; ++s)
                a_h[s] = *(const bf16x8*)&sAh[kk*4096 + (wr + s*16 + ln)*32 + quad*8];
#pragma unroll
            for (int j0 = 0; j0 < 4; ++j0) {
                bf16x8 b_h = *(const bf16x8*)&sBh[kk*4096 + (wc + j0*16 + ln)*32 + quad*8];
#pragma unroll
                for (int s = 0; s < 4; ++s)
                    acc[s][j0] = mfma16(a_h[s], b_h, acc[s][j0]);
            }
        }
    }

    // Q carries 1/8 * log2(e) so attn can use exp2 directly.
    const float scale = (z == 0) ? 0.125f * 1.4426950408889634f : 1.0f;
#pragma unroll
    for (int s = 0; s < 4; ++s) {
#pragma unroll
        for (int j0 = 0; j0 < 4; ++j0) {
            const int dfull = n0 + wc + j0*16 + ln;
            const int hh = dfull >> 6, dd = dfull & 63;
            const float bia = bias[dfull];
#pragma unroll
            for (int i = 0; i < 4; ++i) {
                int m  = m0 + wr + s*16 + quad*4 + i;
                int b_ = m >> 12, l = m & (SEQ-1);
                float v = (acc[s][j0][i] + bia) * scale;
                if (z == 0) {
                    size_t idx = ((size_t)(b_*NUM_HEADS + hh)*SEQ + l)*D_K + dd;
                    Qh[idx] = f2bf(v);
                } else if (z == 1) {
                    size_t idx = ((size_t)(b_*NUM_HEADS + hh)*SEQ + l)*D_K + dd;
                    Kh[idx] = f2bf(v);
                } else {
                    int lp = (l & ~63) | ((l & 15) << 2) | ((l >> 4) & 3);
                    Vh[((size_t)(b_*NUM_HEADS + hh)*D_K + dd)*SEQ + lp] = f2bf(v);
                }
            }
        }
    }
}

// ---------------------------------------------------------------------------
// Output projection, MFMA plain bf16.  R16: same BK=64 two-subtile staging.
// ---------------------------------------------------------------------------
__global__ __launch_bounds__(256)
void out_gemm(const u16* __restrict__ Ah, const u16* __restrict__ Bh_,
              const float* __restrict__ bias, float* __restrict__ C)
{
    __shared__ __align__(16) u16 sAh[2*128*32];
    __shared__ __align__(16) u16 sBh[2*128*32];

    const int tid  = threadIdx.x;
    const int lane = tid & 63;
    const int ln   = lane & 15, quad = lane >> 4;
    const int w    = tid >> 6;
    const int wr   = (w & 1) * 64;
    const int wc   = (w >> 1) * 64;
    const int m0   = blockIdx.x * 128;
    const int n0   = blockIdx.y * 128;
    const int lr = lane >> 2;
    const int lc = (lane & 3) * 8;

    f32x4 acc[4][4];
    const f32x4 z4 = {0.f,0.f,0.f,0.f};
#pragma unroll
    for (int s = 0; s < 4; ++s)
#pragma unroll
        for (int j = 0; j < 4; ++j) acc[s][j] = z4;

#pragma unroll 1
    for (int k0 = 0; k0 < D_MODEL; k0 += 64) {
        __syncthreads();
#pragma unroll
        for (int kk = 0; kk < 2; ++kk) {
#pragma unroll
            for (int cc = 0; cc < 2; ++cc) {
                const int c  = w*2 + cc;
                const int gr = c*16 + lr;
                gload_lds16(&Ah [(size_t)(m0 + gr)*D_MODEL + k0 + kk*32 + lc],
                            &sAh[kk*4096 + c*512]);
                gload_lds16(&Bh_[(size_t)(n0 + gr)*D_MODEL + k0 + kk*32 + lc],
                            &sBh[kk*4096 + c*512]);
            }
        }
        __syncthreads();

#pragma unroll
        for (int kk = 0; kk < 2; ++kk) {
            bf16x8 a_h[4];
#pragma unroll
            for (int s = 0; s < 4; ++s)
                a_h[s] = *(const bf16x8*)&sAh[kk*4096 + (wr + s*16 + ln)*32 + quad*8];
#pragma unroll
            for (int j0 = 0; j0 < 4; ++j0) {
                bf16x8 b_h = *(const bf16x8*)&sBh[kk*4096 + (wc + j0*16 + ln)*32 + quad*8];
#pragma unroll
                for (int s = 0; s < 4; ++s)
                    acc[s][j0] = mfma16(a_h[s], b_h, acc[s][j0]);
            }
        }
    }

#pragma unroll
    for (int s = 0; s < 4; ++s) {
#pragma unroll
        for (int j0 = 0; j0 < 4; ++j0) {
            const int dfull = n0 + wc + j0*16 + ln;
            const float bia = bias[dfull];
#pragma unroll
            for (int i = 0; i < 4; ++i) {
                int m = m0 + wr + s*16 + quad*4 + i;
                C[(size_t)m*D_MODEL + dfull] = acc[s][j0][i] + bia;
            }
        }
    }
}

// ---------------------------------------------------------------------------
// MFMA flash attention — R14 verified version (125.3 µs, absmax 0.98e-3).
// Unchanged this round (control).
// ---------------------------------------------------------------------------
#define LPP 72

__global__ __launch_bounds__(256, 3)
void attn_mfma(const u16* __restrict__ Qh,
               const u16* __restrict__ Kh,
               const u16* __restrict__ Vh, u16* __restrict__ Obh)
{
    __shared__ __align__(16) u16 sK [4096];   // j0*1024 + half*512
    __shared__ __align__(16) u16 sV0[4096];   // d0*1024 + half*512
    __shared__ __align__(16) u16 sV1[4096];
    __shared__ __align__(16) u16 sP [128*LPP];

    const int tid  = threadIdx.x;
    const int w    = tid >> 6;
    const int lane = tid & 63;
    const int ln   = lane & 15;
    const int quad = lane >> 4;
    const int bh   = blockIdx.y;
    const int b_   = bh / NUM_HEADS;
    const int h    = bh % NUM_HEADS;
    const int q0   = blockIdx.x * 128;
    const int wq   = w * 32;
    const int lofs = lane * 8;        // this lane's 16 B frag within a 1 KiB chunk

    const size_t bhL = (size_t)bh * SEQ;
    const u16* __restrict__ Kbh = Kh + bhL * D_K;                 // [key][dk]
    const u16* __restrict__ Vb  = Vh + (size_t)bh * D_K * SEQ;    // [dk][key']

    // Q fragments (A-layout: m=ln, k=quad*8+j)
    bf16x8 qh[2][2];
#pragma unroll
    for (int s = 0; s < 2; ++s) {
        const size_t row = bhL + q0 + wq + s*16 + ln;
        const u16* qph = Qh + row * D_K;
        qh[s][0] = *(const bf16x8*)&qph[quad*8];
        qh[s][1] = *(const bf16x8*)&qph[32 + quad*8];
    }

    const bf16x8 ones = {(short)0x3F80,(short)0x3F80,(short)0x3F80,(short)0x3F80,
                         (short)0x3F80,(short)0x3F80,(short)0x3F80,(short)0x3F80};
    const f32x4 z4 = {0.f,0.f,0.f,0.f};
    f32x4 lacc[2] = {z4, z4};
    f32x4 o[2][4];
#pragma unroll
    for (int s = 0; s < 2; ++s)
#pragma unroll
        for (int d0 = 0; d0 < 4; ++d0) o[s][d0] = z4;

    // ---- prologue: DMA tile 0 (wave w stages K j0=w and V d0=w) ----
    gload_lds16(Vb + (size_t)(w*16 + ln)*SEQ + quad*8,      &sV0[w*1024]);
    gload_lds16(Vb + (size_t)(w*16 + ln)*SEQ + 32 + quad*8, &sV0[w*1024 + 512]);
#pragma unroll
    for (int t = 0; t < 2; ++t) {
        gload_lds16(Kbh + (size_t)(w*16 + ln)*D_K + t*32 + quad*8,
                    &sK[w*1024 + t*512]);
    }

#define ATTN_BODY(SVC, SVN, KTN)                                               \
    {                                                                          \
        __syncthreads();  /* drains vmcnt: this tile's K+V DMAs visible */     \
        /* V prefetch for next tile (other buffer: released by the barrier) */ \
        gload_lds16(Vb + (size_t)(w*16 + ln)*SEQ + (KTN) + quad*8,             \
                    &SVN[w*1024]);                                             \
        gload_lds16(Vb + (size_t)(w*16 + ln)*SEQ + (KTN) + 32 + quad*8,        \
                    &SVN[w*1024 + 512]);                                       \
        /* S = Q K^T : Q plain, K plain (2 mfma per s,j0) */                   \
        f32x4 S[2][4];                                                         \
        __builtin_amdgcn_s_setprio(1);                                         \
        _Pragma("unroll")                                                      \
        for (int j0 = 0; j0 < 4; ++j0) {                                       \
            bf16x8 kh0 = *(const bf16x8*)&sK[j0*1024       + lofs];            \
            bf16x8 kh1 = *(const bf16x8*)&sK[j0*1024 + 512 + lofs];            \
            _Pragma("unroll")                                                  \
            for (int s = 0; s < 2; ++s) {                                      \
                f32x4 a = z4;                                                  \
                a = mfma16(qh[s][0], kh0, a);                                  \
                a = mfma16(qh[s][1], kh1, a);                                  \
                S[s][j0] = a;                                                  \
            }                                                                  \
        }                                                                      \
        __builtin_amdgcn_s_setprio(0);                                         \
        /* all waves' K reads retired -> release sK, prefetch next K tile */   \
        asm volatile("s_waitcnt lgkmcnt(0)\n\ts_barrier" ::: "memory");        \
        _Pragma("unroll")                                                      \
        for (int t = 0; t < 2; ++t) {                                          \
            gload_lds16(Kbh + (size_t)((KTN) + w*16 + ln)*D_K + t*32 + quad*8, \
                        &sK[w*1024 + t*512]);                                  \
        }                                                                      \
        /* P = exp2(S); trunc-pack via v_perm into wave-private sP */          \
        _Pragma("unroll")                                                      \
        for (int s = 0; s < 2; ++s) {                                          \
            _Pragma("unroll")                                                  \
            for (int i = 0; i < 4; ++i) {                                      \
                u32 u0 = __float_as_uint(fast_exp2(S[s][0][i]));               \
                u32 u1 = __float_as_uint(fast_exp2(S[s][1][i]));               \
                u32 u2 = __float_as_uint(fast_exp2(S[s][2][i]));               \
                u32 u3 = __float_as_uint(fast_exp2(S[s][3][i]));               \
                uint2 pk;                                                      \
                pk.x = __builtin_amdgcn_perm(u1, u0, 0x07060302u);             \
                pk.y = __builtin_amdgcn_perm(u3, u2, 0x07060302u);             \
                int prow = wq + s*16 + quad*4 + i;                             \
                *(uint2*)&sP[prow*LPP + ln*4] = pk;                            \
            }                                                                  \
        }                                                                      \
        /* O += P V ; l += P @ ones  (sP wave-private: no barrier) */          \
        bf16x8 pa[2][2];                                                       \
        _Pragma("unroll")                                                      \
        for (int s = 0; s < 2; ++s) {                                          \
            const u16* pp = &sP[(wq + s*16 + ln)*LPP];                         \
            pa[s][0] = *(const bf16x8*)&pp[quad*8];                            \
            pa[s][1] = *(const bf16x8*)&pp[32 + quad*8];                       \
        }                                                                      \
        __builtin_amdgcn_s_setprio(1);                                         \
        _Pragma("unroll")                                                      \
        for (int s = 0; s < 2; ++s) {                                          \
            lacc[s] = mfma16(pa[s][0], ones, lacc[s]);                         \
            lacc[s] = mfma16(pa[s][1], ones, lacc[s]);                         \
        }                                                                      \
        _Pragma("unroll")                                                      \
        for (int d0 = 0; d0 < 4; ++d0) {                                       \
            bf16x8 vh0 = *(const bf16x8*)&SVC[d0*1024       + lofs];           \
            bf16x8 vh1 = *(const bf16x8*)&SVC[d0*1024 + 512 + lofs];           \
            _Pragma("unroll")                                                  \
            for (int s = 0; s < 2; ++s) {                                      \
                f32x4 a = o[s][d0];                                            \
                a = mfma16(pa[s][0], vh0, a);                                  \
                a = mfma16(pa[s][1], vh1, a);                                  \
                o[s][d0] = a;                                                  \
            }                                                                  \
        }                                                                      \
        __builtin_amdgcn_s_setprio(0);                                         \
    }

#pragma unroll 1
    for (int kt = 0; kt < SEQ; kt += 128) {
        const int kn1 = kt + 64;
        const int kn2 = (kt + 128 == SEQ) ? 0 : kt + 128;   // wrap: harmless
        ATTN_BODY(sV0, sV1, kn1)
        ATTN_BODY(sV1, sV0, kn2)
    }
#undef ATTN_BODY

    // ---- epilogue: l row-sums already in lacc (all lanes); store bf16 ----
#pragma unroll
    for (int s = 0; s < 2; ++s) {
        float inv[4];
#pragma unroll
        for (int i = 0; i < 4; ++i) inv[i] = 1.0f / lacc[s][i];
#pragma unroll
        for (int d0 = 0; d0 < 4; ++d0) {
#pragma unroll
            for (int i = 0; i < 4; ++i) {
                int q = q0 + wq + s*16 + quad*4 + i;
                Obh[((size_t)b_*SEQ + q)*D_MODEL + h*D_K + d0*16 + ln] =
                    f2bf(o[s][d0][i] * inv[i]);
            }
        }
    }
}

extern "C" void kernel_launch(void* const* d_in, const int* in_sizes, int n_in,
                              void* d_out, int out_size, void* d_ws, size_t ws_size,
                              hipStream_t stream)
{
    const float* x  = (const float*)d_in[0];
    const float* Wq = (const float*)d_in[1];
    const float* bq = (const float*)d_in[2];
    const float* Wk = (const float*)d_in[3];
    const float* bk = (const float*)d_in[4];
    const float* Wv = (const float*)d_in[5];
    const float* bv = (const float*)d_in[6];
    const float* Wo = (const float*)d_in[7];
    const float* bo = (const float*)d_in[8];
    float* out = (float*)d_out;

    const size_t nX = (size_t)MROWS * D_MODEL;    // 6291456
    const size_t nW = (size_t)D_MODEL * D_MODEL;  // 589824

    u16* Xh  = (u16*)d_ws;
    u16* Wqh = Xh  + nX;
    u16* Wkh = Wqh + nW;
    u16* Wvh = Wkh + nW;
    u16* Woh = Wvh + nW;
    u16* Qh  = Woh + nW;
    u16* Kh  = Qh  + nX;
    u16* Vh  = Kh  + nX;
    u16* Obh = Xh;                 // alias: Xh dead after proj_gemm

    dim3 blk(256);
    convert_x<<<dim3(nX/(256*8)), blk, 0, stream>>>(x, Xh);
    convert_w<<<dim3(nW/(256*8), 4), blk, 0, stream>>>(Wq, Wk, Wv, Wo,
                                                       Wqh, Wkh, Wvh, Woh);
    proj_gemm<<<dim3(MROWS/128, D_MODEL/128, 3), blk, 0, stream>>>(
        Xh, Wqh, Wkh, Wvh, bq, bk, bv, Qh, Kh, Vh);
    attn_mfma<<<dim3(SEQ/128, BH_), blk, 0, stream>>>(Qh, Kh, Vh, Obh);
    out_gemm<<<dim3(MROWS/128, D_MODEL/128), blk, 0, stream>>>(Obh, Woh, bo, out);
}

// Round 17
// 288.419 us; speedup vs baseline: 1.0378x; 1.0378x over previous
//
#include <hip/hip_runtime.h>
#include <math.h>

#define D_MODEL 768
#define NUM_HEADS 12
#define D_K 64
#define SEQ 4096
#define BATCH 2
#define BH_ (BATCH*NUM_HEADS)
#define MROWS (BATCH*SEQ)     // 8192

typedef __attribute__((ext_vector_type(8))) short bf16x8;
typedef __attribute__((ext_vector_type(4))) float f32x4;
typedef unsigned short u16;
typedef unsigned int u32;

__device__ __forceinline__ u16 f2bf(float f) {
    union { float f; u32 u; } v; v.f = f;
    u32 r = v.u + 0x7fffu + ((v.u >> 16) & 1u);   // RNE
    return (u16)(r >> 16);
}
__device__ __forceinline__ float fast_exp2(float x) {
#if __has_builtin(__builtin_amdgcn_exp2f)
    return __builtin_amdgcn_exp2f(x);
#else
    return exp2f(x);
#endif
}
// async global->LDS DMA: LDS dest = uniform base + lane*16
__device__ __forceinline__ void gload_lds16(const u16* g, u16* l) {
    __builtin_amdgcn_global_load_lds(
        (const __attribute__((address_space(1))) void*)g,
        (__attribute__((address_space(3))) void*)l, 16, 0, 0);
}
__device__ __forceinline__ f32x4 mfma16(bf16x8 a, bf16x8 b, f32x4 c) {
    return __builtin_amdgcn_mfma_f32_16x16x32_bf16(a, b, c, 0, 0, 0);
}

// ---------------------------------------------------------------------------
// R17: single fused convert launch.  1-D grid:
//   blocks [0, nX/2048)                -> x -> Xh
//   blocks [nX/2048 + z*nW/2048 ...)   -> W[z] -> Wzh   (z = 0..3)
// 8 f32 -> 8 bf16 per thread, RNE.  Math identical to the split kernels.
// ---------------------------------------------------------------------------
#define XBLKS (MROWS*D_MODEL/2048)   // 3072
#define WBLKS (D_MODEL*D_MODEL/2048) // 288

__global__ __launch_bounds__(256)
void convert_all(const float* __restrict__ x,
                 const float* __restrict__ Wq, const float* __restrict__ Wk,
                 const float* __restrict__ Wv, const float* __restrict__ Wo,
                 u16* __restrict__ Xh,
                 u16* __restrict__ Wqh, u16* __restrict__ Wkh,
                 u16* __restrict__ Wvh, u16* __restrict__ Woh)
{
    int b = blockIdx.x;
    const float* src;
    u16* dst;
    if (b < XBLKS) {
        src = x; dst = Xh;
    } else {
        int wb = b - XBLKS;
        int z  = wb / WBLKS;
        b      = wb - z * WBLKS;
        src = (z==0)?Wq:(z==1)?Wk:(z==2)?Wv:Wo;
        dst = (z==0)?Wqh:(z==1)?Wkh:(z==2)?Wvh:Woh;
    }
    int i = (b * 256 + threadIdx.x) * 8;
    float4 a = *(const float4*)&src[i];
    float4 c = *(const float4*)&src[i + 4];
    u16 h0 = f2bf(a.x), h1 = f2bf(a.y), h2 = f2bf(a.z), h3 = f2bf(a.w);
    u16 h4 = f2bf(c.x), h5 = f2bf(c.y), h6 = f2bf(c.z), h7 = f2bf(c.w);
    uint4 H;
    H.x = (u32)h0 | ((u32)h1 << 16); H.y = (u32)h2 | ((u32)h3 << 16);
    H.z = (u32)h4 | ((u32)h5 << 16); H.w = (u32)h6 | ((u32)h7 << 16);
    *(uint4*)&dst[i] = H;
}

// ---------------------------------------------------------------------------
// QKV projection, MFMA.  128x128 tile, BK=32, 4 waves (2x2 of 64x64).
// R15-verified form (BK=64 regressed in R16 and was reverted).
// ---------------------------------------------------------------------------
__global__ __launch_bounds__(256)
void proj_gemm(const u16* __restrict__ Xh,
               const u16* __restrict__ Wqh, const u16* __restrict__ Wkh,
               const u16* __restrict__ Wvh,
               const float* __restrict__ bq, const float* __restrict__ bk,
               const float* __restrict__ bv,
               u16* __restrict__ Qh, u16* __restrict__ Kh, u16* __restrict__ Vh)
{
    const int z = blockIdx.z;
    const u16* __restrict__ Bh_ = (z==0)?Wqh:(z==1)?Wkh:Wvh;
    const float* __restrict__ bias = (z==0)?bq:(z==1)?bk:bv;

    __shared__ __align__(16) u16 sAh[128*32];
    __shared__ __align__(16) u16 sBh[128*32];

    const int tid  = threadIdx.x;
    const int lane = tid & 63;
    const int ln   = lane & 15, quad = lane >> 4;
    const int w    = tid >> 6;
    const int wr   = (w & 1) * 64;
    const int wc   = (w >> 1) * 64;
    const int m0   = blockIdx.x * 128;
    const int n0   = blockIdx.y * 128;

    const int lr = lane >> 2;          // 0..15 row within 16-row chunk
    const int lc = (lane & 3) * 8;     // u16 col (0,8,16,24)

    f32x4 acc[4][4];
    const f32x4 z4 = {0.f,0.f,0.f,0.f};
#pragma unroll
    for (int s = 0; s < 4; ++s)
#pragma unroll
        for (int j = 0; j < 4; ++j) acc[s][j] = z4;

#pragma unroll 1
    for (int k0 = 0; k0 < D_MODEL; k0 += 32) {
        __syncthreads();   // previous tile fully consumed before DMA overwrite
#pragma unroll
        for (int cc = 0; cc < 2; ++cc) {
            const int c  = w*2 + cc;        // chunk 0..7 (16 rows each)
            const int gr = c*16 + lr;
            gload_lds16(&Xh [(size_t)(m0 + gr)*D_MODEL + k0 + lc], &sAh[c*512]);
            gload_lds16(&Bh_[(size_t)(n0 + gr)*D_MODEL + k0 + lc], &sBh[c*512]);
        }
        __syncthreads();   // drains vmcnt -> DMA data visible

        bf16x8 a_h[4];
#pragma unroll
        for (int s = 0; s < 4; ++s)
            a_h[s] = *(const bf16x8*)&sAh[(wr + s*16 + ln)*32 + quad*8];
#pragma unroll
        for (int j0 = 0; j0 < 4; ++j0) {
            bf16x8 b_h = *(const bf16x8*)&sBh[(wc + j0*16 + ln)*32 + quad*8];
#pragma unroll
            for (int s = 0; s < 4; ++s)
                acc[s][j0] = mfma16(a_h[s], b_h, acc[s][j0]);
        }
    }

    // Q carries 1/8 * log2(e) so attn can use exp2 directly.
    const float scale = (z == 0) ? 0.125f * 1.4426950408889634f : 1.0f;
#pragma unroll
    for (int s = 0; s < 4; ++s) {
#pragma unroll
        for (int j0 = 0; j0 < 4; ++j0) {
            const int dfull = n0 + wc + j0*16 + ln;
            const int hh = dfull >> 6, dd = dfull & 63;
            const float bia = bias[dfull];
#pragma unroll
            for (int i = 0; i < 4; ++i) {
                int m  = m0 + wr + s*16 + quad*4 + i;
                int b_ = m >> 12, l = m & (SEQ-1);
                float v = (acc[s][j0][i] + bia) * scale;
                if (z == 0) {
                    size_t idx = ((size_t)(b_*NUM_HEADS + hh)*SEQ + l)*D_K + dd;
                    Qh[idx] = f2bf(v);
                } else if (z == 1) {
                    size_t idx = ((size_t)(b_*NUM_HEADS + hh)*SEQ + l)*D_K + dd;
                    Kh[idx] = f2bf(v);
                } else {
                    int lp = (l & ~63) | ((l & 15) << 2) | ((l >> 4) & 3);
                    Vh[((size_t)(b_*NUM_HEADS + hh)*D_K + dd)*SEQ + lp] = f2bf(v);
                }
            }
        }
    }
}

// ---------------------------------------------------------------------------
// Output projection, MFMA plain bf16, global_load_lds staging (R15 form).
// ---------------------------------------------------------------------------
__global__ __launch_bounds__(256)
void out_gemm(const u16* __restrict__ Ah, const u16* __restrict__ Bh_,
              const float* __restrict__ bias, float* __restrict__ C)
{
    __shared__ __align__(16) u16 sAh[128*32];
    __shared__ __align__(16) u16 sBh[128*32];

    const int tid  = threadIdx.x;
    const int lane = tid & 63;
    const int ln   = lane & 15, quad = lane >> 4;
    const int w    = tid >> 6;
    const int wr   = (w & 1) * 64;
    const int wc   = (w >> 1) * 64;
    const int m0   = blockIdx.x * 128;
    const int n0   = blockIdx.y * 128;
    const int lr = lane >> 2;
    const int lc = (lane & 3) * 8;

    f32x4 acc[4][4];
    const f32x4 z4 = {0.f,0.f,0.f,0.f};
#pragma unroll
    for (int s = 0; s < 4; ++s)
#pragma unroll
        for (int j = 0; j < 4; ++j) acc[s][j] = z4;

#pragma unroll 1
    for (int k0 = 0; k0 < D_MODEL; k0 += 32) {
        __syncthreads();
#pragma unroll
        for (int cc = 0; cc < 2; ++cc) {
            const int c  = w*2 + cc;
            const int gr = c*16 + lr;
            gload_lds16(&Ah [(size_t)(m0 + gr)*D_MODEL + k0 + lc], &sAh[c*512]);
            gload_lds16(&Bh_[(size_t)(n0 + gr)*D_MODEL + k0 + lc], &sBh[c*512]);
        }
        __syncthreads();

        bf16x8 a_h[4];
#pragma unroll
        for (int s = 0; s < 4; ++s)
            a_h[s] = *(const bf16x8*)&sAh[(wr + s*16 + ln)*32 + quad*8];
#pragma unroll
        for (int j0 = 0; j0 < 4; ++j0) {
            bf16x8 b_h = *(const bf16x8*)&sBh[(wc + j0*16 + ln)*32 + quad*8];
#pragma unroll
            for (int s = 0; s < 4; ++s)
                acc[s][j0] = mfma16(a_h[s], b_h, acc[s][j0]);
        }
    }

#pragma unroll
    for (int s = 0; s < 4; ++s) {
#pragma unroll
        for (int j0 = 0; j0 < 4; ++j0) {
            const int dfull = n0 + wc + j0*16 + ln;
            const float bia = bias[dfull];
#pragma unroll
            for (int i = 0; i < 4; ++i) {
                int m = m0 + wr + s*16 + quad*4 + i;
                C[(size_t)m*D_MODEL + dfull] = acc[s][j0][i] + bia;
            }
        }
    }
}

// ---------------------------------------------------------------------------
// MFMA flash attention — R14 verified version (125.3 µs, absmax 0.98e-3).
// Unchanged (control).
// ---------------------------------------------------------------------------
#define LPP 72

__global__ __launch_bounds__(256, 3)
void attn_mfma(const u16* __restrict__ Qh,
               const u16* __restrict__ Kh,
               const u16* __restrict__ Vh, u16* __restrict__ Obh)
{
    __shared__ __align__(16) u16 sK [4096];   // j0*1024 + half*512
    __shared__ __align__(16) u16 sV0[4096];   // d0*1024 + half*512
    __shared__ __align__(16) u16 sV1[4096];
    __shared__ __align__(16) u16 sP [128*LPP];

    const int tid  = threadIdx.x;
    const int w    = tid >> 6;
    const int lane = tid & 63;
    const int ln   = lane & 15;
    const int quad = lane >> 4;
    const int bh   = blockIdx.y;
    const int b_   = bh / NUM_HEADS;
    const int h    = bh % NUM_HEADS;
    const int q0   = blockIdx.x * 128;
    const int wq   = w * 32;
    const int lofs = lane * 8;        // this lane's 16 B frag within a 1 KiB chunk

    const size_t bhL = (size_t)bh * SEQ;
    const u16* __restrict__ Kbh = Kh + bhL * D_K;                 // [key][dk]
    const u16* __restrict__ Vb  = Vh + (size_t)bh * D_K * SEQ;    // [dk][key']

    // Q fragments (A-layout: m=ln, k=quad*8+j)
    bf16x8 qh[2][2];
#pragma unroll
    for (int s = 0; s < 2; ++s) {
        const size_t row = bhL + q0 + wq + s*16 + ln;
        const u16* qph = Qh + row * D_K;
        qh[s][0] = *(const bf16x8*)&qph[quad*8];
        qh[s][1] = *(const bf16x8*)&qph[32 + quad*8];
    }

    const bf16x8 ones = {(short)0x3F80,(short)0x3F80,(short)0x3F80,(short)0x3F80,
                         (short)0x3F80,(short)0x3F80,(short)0x3F80,(short)0x3F80};
    const f32x4 z4 = {0.f,0.f,0.f,0.f};
    f32x4 lacc[2] = {z4, z4};
    f32x4 o[2][4];
#pragma unroll
    for (int s = 0; s < 2; ++s)
#pragma unroll
        for (int d0 = 0; d0 < 4; ++d0) o[s][d0] = z4;

    // ---- prologue: DMA tile 0 (wave w stages K j0=w and V d0=w) ----
    gload_lds16(Vb + (size_t)(w*16 + ln)*SEQ + quad*8,      &sV0[w*1024]);
    gload_lds16(Vb + (size_t)(w*16 + ln)*SEQ + 32 + quad*8, &sV0[w*1024 + 512]);
#pragma unroll
    for (int t = 0; t < 2; ++t) {
        gload_lds16(Kbh + (size_t)(w*16 + ln)*D_K + t*32 + quad*8,
                    &sK[w*1024 + t*512]);
    }

#define ATTN_BODY(SVC, SVN, KTN)                                               \
    {                                                                          \
        __syncthreads();  /* drains vmcnt: this tile's K+V DMAs visible */     \
        /* V prefetch for next tile (other buffer: released by the barrier) */ \
        gload_lds16(Vb + (size_t)(w*16 + ln)*SEQ + (KTN) + quad*8,             \
                    &SVN[w*1024]);                                             \
        gload_lds16(Vb + (size_t)(w*16 + ln)*SEQ + (KTN) + 32 + quad*8,        \
                    &SVN[w*1024 + 512]);                                       \
        /* S = Q K^T : Q plain, K plain (2 mfma per s,j0) */                   \
        f32x4 S[2][4];                                                         \
        __builtin_amdgcn_s_setprio(1);                                         \
        _Pragma("unroll")                                                      \
        for (int j0 = 0; j0 < 4; ++j0) {                                       \
            bf16x8 kh0 = *(const bf16x8*)&sK[j0*1024       + lofs];            \
            bf16x8 kh1 = *(const bf16x8*)&sK[j0*1024 + 512 + lofs];            \
            _Pragma("unroll")                                                  \
            for (int s = 0; s < 2; ++s) {                                      \
                f32x4 a = z4;                                                  \
                a = mfma16(qh[s][0], kh0, a);                                  \
                a = mfma16(qh[s][1], kh1, a);                                  \
                S[s][j0] = a;                                                  \
            }                                                                  \
        }                                                                      \
        __builtin_amdgcn_s_setprio(0);                                         \
        /* all waves' K reads retired -> release sK, prefetch next K tile */   \
        asm volatile("s_waitcnt lgkmcnt(0)\n\ts_barrier" ::: "memory");        \
        _Pragma("unroll")                                                      \
        for (int t = 0; t < 2; ++t) {                                          \
            gload_lds16(Kbh + (size_t)((KTN) + w*16 + ln)*D_K + t*32 + quad*8, \
                        &sK[w*1024 + t*512]);                                  \
        }                                                                      \
        /* P = exp2(S); trunc-pack via v_perm into wave-private sP */          \
        _Pragma("unroll")                                                      \
        for (int s = 0; s < 2; ++s) {                                          \
            _Pragma("unroll")                                                  \
            for (int i = 0; i < 4; ++i) {                                      \
                u32 u0 = __float_as_uint(fast_exp2(S[s][0][i]));               \
                u32 u1 = __float_as_uint(fast_exp2(S[s][1][i]));               \
                u32 u2 = __float_as_uint(fast_exp2(S[s][2][i]));               \
                u32 u3 = __float_as_uint(fast_exp2(S[s][3][i]));               \
                uint2 pk;                                                      \
                pk.x = __builtin_amdgcn_perm(u1, u0, 0x07060302u);             \
                pk.y = __builtin_amdgcn_perm(u3, u2, 0x07060302u);             \
                int prow = wq + s*16 + quad*4 + i;                             \
                *(uint2*)&sP[prow*LPP + ln*4] = pk;                            \
            }                                                                  \
        }                                                                      \
        /* O += P V ; l += P @ ones  (sP wave-private: no barrier) */          \
        bf16x8 pa[2][2];                                                       \
        _Pragma("unroll")                                                      \
        for (int s = 0; s < 2; ++s) {                                          \
            const u16* pp = &sP[(wq + s*16 + ln)*LPP];                         \
            pa[s][0] = *(const bf16x8*)&pp[quad*8];                            \
            pa[s][1] = *(const bf16x8*)&pp[32 + quad*8];                       \
        }                                                                      \
        __builtin_amdgcn_s_setprio(1);                                         \
        _Pragma("unroll")                                                      \
        for (int s = 0; s < 2; ++s) {                                          \
            lacc[s] = mfma16(pa[s][0], ones, lacc[s]);                         \
            lacc[s] = mfma16(pa[s][1], ones, lacc[s]);                         \
        }                                                                      \
        _Pragma("unroll")                                                      \
        for (int d0 = 0; d0 < 4; ++d0) {                                       \
            bf16x8 vh0 = *(const bf16x8*)&SVC[d0*1024       + lofs];           \
            bf16x8 vh1 = *(const bf16x8*)&SVC[d0*1024 + 512 + lofs];           \
            _Pragma("unroll")                                                  \
            for (int s = 0; s < 2; ++s) {                                      \
                f32x4 a = o[s][d0];                                            \
                a = mfma16(pa[s][0], vh0, a);                                  \
                a = mfma16(pa[s][1], vh1, a);                                  \
                o[s][d0] = a;                                                  \
            }                                                                  \
        }                                                                      \
        __builtin_amdgcn_s_setprio(0);                                         \
    }

#pragma unroll 1
    for (int kt = 0; kt < SEQ; kt += 128) {
        const int kn1 = kt + 64;
        const int kn2 = (kt + 128 == SEQ) ? 0 : kt + 128;   // wrap: harmless
        ATTN_BODY(sV0, sV1, kn1)
        ATTN_BODY(sV1, sV0, kn2)
    }
#undef ATTN_BODY

    // ---- epilogue: l row-sums already in lacc (all lanes); store bf16 ----
#pragma unroll
    for (int s = 0; s < 2; ++s) {
        float inv[4];
#pragma unroll
        for (int i = 0; i < 4; ++i) inv[i] = 1.0f / lacc[s][i];
#pragma unroll
        for (int d0 = 0; d0 < 4; ++d0) {
#pragma unroll
            for (int i = 0; i < 4; ++i) {
                int q = q0 + wq + s*16 + quad*4 + i;
                Obh[((size_t)b_*SEQ + q)*D_MODEL + h*D_K + d0*16 + ln] =
                    f2bf(o[s][d0][i] * inv[i]);
            }
        }
    }
}

extern "C" void kernel_launch(void* const* d_in, const int* in_sizes, int n_in,
                              void* d_out, int out_size, void* d_ws, size_t ws_size,
                              hipStream_t stream)
{
    const float* x  = (const float*)d_in[0];
    const float* Wq = (const float*)d_in[1];
    const float* bq = (const float*)d_in[2];
    const float* Wk = (const float*)d_in[3];
    const float* bk = (const float*)d_in[4];
    const float* Wv = (const float*)d_in[5];
    const float* bv = (const float*)d_in[6];
    const float* Wo = (const float*)d_in[7];
    const float* bo = (const float*)d_in[8];
    float* out = (float*)d_out;

    const size_t nX = (size_t)MROWS * D_MODEL;    // 6291456
    const size_t nW = (size_t)D_MODEL * D_MODEL;  // 589824

    u16* Xh  = (u16*)d_ws;
    u16* Wqh = Xh  + nX;
    u16* Wkh = Wqh + nW;
    u16* Wvh = Wkh + nW;
    u16* Woh = Wvh + nW;
    u16* Qh  = Woh + nW;
    u16* Kh  = Qh  + nX;
    u16* Vh  = Kh  + nX;
    u16* Obh = Xh;                 // alias: Xh dead after proj_gemm

    dim3 blk(256);
    convert_all<<<dim3(XBLKS + 4*WBLKS), blk, 0, stream>>>(
        x, Wq, Wk, Wv, Wo, Xh, Wqh, Wkh, Wvh, Woh);
    proj_gemm<<<dim3(MROWS/128, D_MODEL/128, 3), blk, 0, stream>>>(
        Xh, Wqh, Wkh, Wvh, bq, bk, bv, Qh, Kh, Vh);
    attn_mfma<<<dim3(SEQ/128, BH_), blk, 0, stream>>>(Qh, Kh, Vh, Obh);
    out_gemm<<<dim3(MROWS/128, D_MODEL/128), blk, 0, stream>>>(Obh, Woh, bo, out);
}

// Round 19
// 285.368 us; speedup vs baseline: 1.0489x; 1.0107x over previous
//
#include <hip/hip_runtime.h>
#include <math.h>

#define D_MODEL 768
#define NUM_HEADS 12
#define D_K 64
#define SEQ 4096
#define BATCH 2
#define BH_ (BATCH*NUM_HEADS)
#define MROWS (BATCH*SEQ)     // 8192

typedef __attribute__((ext_vector_type(8))) short bf16x8;
typedef __attribute__((ext_vector_type(4))) float f32x4;
typedef unsigned short u16;
typedef unsigned int u32;

__device__ __forceinline__ u16 f2bf(float f) {
    union { float f; u32 u; } v; v.f = f;
    u32 r = v.u + 0x7fffu + ((v.u >> 16) & 1u);   // RNE
    return (u16)(r >> 16);
}
__device__ __forceinline__ float fast_exp2(float x) {
#if __has_builtin(__builtin_amdgcn_exp2f)
    return __builtin_amdgcn_exp2f(x);
#else
    return exp2f(x);
#endif
}
// async global->LDS DMA: LDS dest = uniform base + lane*16
__device__ __forceinline__ void gload_lds16(const u16* g, u16* l) {
    __builtin_amdgcn_global_load_lds(
        (const __attribute__((address_space(1))) void*)g,
        (__attribute__((address_space(3))) void*)l, 16, 0, 0);
}
__device__ __forceinline__ f32x4 mfma16(bf16x8 a, bf16x8 b, f32x4 c) {
    return __builtin_amdgcn_mfma_f32_16x16x32_bf16(a, b, c, 0, 0, 0);
}

// ---------------------------------------------------------------------------
// R17: single fused convert launch (verified).
// ---------------------------------------------------------------------------
#define XBLKS (MROWS*D_MODEL/2048)   // 3072
#define WBLKS (D_MODEL*D_MODEL/2048) // 288

__global__ __launch_bounds__(256)
void convert_all(const float* __restrict__ x,
                 const float* __restrict__ Wq, const float* __restrict__ Wk,
                 const float* __restrict__ Wv, const float* __restrict__ Wo,
                 u16* __restrict__ Xh,
                 u16* __restrict__ Wqh, u16* __restrict__ Wkh,
                 u16* __restrict__ Wvh, u16* __restrict__ Woh)
{
    int b = blockIdx.x;
    const float* src;
    u16* dst;
    if (b < XBLKS) {
        src = x; dst = Xh;
    } else {
        int wb = b - XBLKS;
        int z  = wb / WBLKS;
        b      = wb - z * WBLKS;
        src = (z==0)?Wq:(z==1)?Wk:(z==2)?Wv:Wo;
        dst = (z==0)?Wqh:(z==1)?Wkh:(z==2)?Wvh:Woh;
    }
    int i = (b * 256 + threadIdx.x) * 8;
    float4 a = *(const float4*)&src[i];
    float4 c = *(const float4*)&src[i + 4];
    u16 h0 = f2bf(a.x), h1 = f2bf(a.y), h2 = f2bf(a.z), h3 = f2bf(a.w);
    u16 h4 = f2bf(c.x), h5 = f2bf(c.y), h6 = f2bf(c.z), h7 = f2bf(c.w);
    uint4 H;
    H.x = (u32)h0 | ((u32)h1 << 16); H.y = (u32)h2 | ((u32)h3 << 16);
    H.z = (u32)h4 | ((u32)h5 << 16); H.w = (u32)h6 | ((u32)h7 << 16);
    *(uint4*)&dst[i] = H;
}

// ---------------------------------------------------------------------------
// QKV projection, MFMA.  128x128 tile, BK=32, 4 waves (2x2 of 64x64).
// R15-verified form.
// ---------------------------------------------------------------------------
__global__ __launch_bounds__(256)
void proj_gemm(const u16* __restrict__ Xh,
               const u16* __restrict__ Wqh, const u16* __restrict__ Wkh,
               const u16* __restrict__ Wvh,
               const float* __restrict__ bq, const float* __restrict__ bk,
               const float* __restrict__ bv,
               u16* __restrict__ Qh, u16* __restrict__ Kh, u16* __restrict__ Vh)
{
    const int z = blockIdx.z;
    const u16* __restrict__ Bh_ = (z==0)?Wqh:(z==1)?Wkh:Wvh;
    const float* __restrict__ bias = (z==0)?bq:(z==1)?bk:bv;

    __shared__ __align__(16) u16 sAh[128*32];
    __shared__ __align__(16) u16 sBh[128*32];

    const int tid  = threadIdx.x;
    const int lane = tid & 63;
    const int ln   = lane & 15, quad = lane >> 4;
    const int w    = tid >> 6;
    const int wr   = (w & 1) * 64;
    const int wc   = (w >> 1) * 64;
    const int m0   = blockIdx.x * 128;
    const int n0   = blockIdx.y * 128;

    const int lr = lane >> 2;          // 0..15 row within 16-row chunk
    const int lc = (lane & 3) * 8;     // u16 col (0,8,16,24)

    f32x4 acc[4][4];
    const f32x4 z4 = {0.f,0.f,0.f,0.f};
#pragma unroll
    for (int s = 0; s < 4; ++s)
#pragma unroll
        for (int j = 0; j < 4; ++j) acc[s][j] = z4;

#pragma unroll 1
    for (int k0 = 0; k0 < D_MODEL; k0 += 32) {
        __syncthreads();   // previous tile fully consumed before DMA overwrite
#pragma unroll
        for (int cc = 0; cc < 2; ++cc) {
            const int c  = w*2 + cc;        // chunk 0..7 (16 rows each)
            const int gr = c*16 + lr;
            gload_lds16(&Xh [(size_t)(m0 + gr)*D_MODEL + k0 + lc], &sAh[c*512]);
            gload_lds16(&Bh_[(size_t)(n0 + gr)*D_MODEL + k0 + lc], &sBh[c*512]);
        }
        __syncthreads();   // drains vmcnt -> DMA data visible

        bf16x8 a_h[4];
#pragma unroll
        for (int s = 0; s < 4; ++s)
            a_h[s] = *(const bf16x8*)&sAh[(wr + s*16 + ln)*32 + quad*8];
#pragma unroll
        for (int j0 = 0; j0 < 4; ++j0) {
            bf16x8 b_h = *(const bf16x8*)&sBh[(wc + j0*16 + ln)*32 + quad*8];
#pragma unroll
            for (int s = 0; s < 4; ++s)
                acc[s][j0] = mfma16(a_h[s], b_h, acc[s][j0]);
        }
    }

    // Q carries 1/8 * log2(e) so attn can use exp2 directly.
    const float scale = (z == 0) ? 0.125f * 1.4426950408889634f : 1.0f;
#pragma unroll
    for (int s = 0; s < 4; ++s) {
#pragma unroll
        for (int j0 = 0; j0 < 4; ++j0) {
            const int dfull = n0 + wc + j0*16 + ln;
            const int hh = dfull >> 6, dd = dfull & 63;
            const float bia = bias[dfull];
#pragma unroll
            for (int i = 0; i < 4; ++i) {
                int m  = m0 + wr + s*16 + quad*4 + i;
                int b_ = m >> 12, l = m & (SEQ-1);
                float v = (acc[s][j0][i] + bia) * scale;
                if (z == 0) {
                    size_t idx = ((size_t)(b_*NUM_HEADS + hh)*SEQ + l)*D_K + dd;
                    Qh[idx] = f2bf(v);
                } else if (z == 1) {
                    size_t idx = ((size_t)(b_*NUM_HEADS + hh)*SEQ + l)*D_K + dd;
                    Kh[idx] = f2bf(v);
                } else {
                    int lp = (l & ~63) | ((l & 15) << 2) | ((l >> 4) & 3);
                    Vh[((size_t)(b_*NUM_HEADS + hh)*D_K + dd)*SEQ + lp] = f2bf(v);
                }
            }
        }
    }
}

// ---------------------------------------------------------------------------
// Output projection, MFMA plain bf16, global_load_lds staging (R15 form).
// ---------------------------------------------------------------------------
__global__ __launch_bounds__(256)
void out_gemm(const u16* __restrict__ Ah, const u16* __restrict__ Bh_,
              const float* __restrict__ bias, float* __restrict__ C)
{
    __shared__ __align__(16) u16 sAh[128*32];
    __shared__ __align__(16) u16 sBh[128*32];

    const int tid  = threadIdx.x;
    const int lane = tid & 63;
    const int ln   = lane & 15, quad = lane >> 4;
    const int w    = tid >> 6;
    const int wr   = (w & 1) * 64;
    const int wc   = (w >> 1) * 64;
    const int m0   = blockIdx.x * 128;
    const int n0   = blockIdx.y * 128;
    const int lr = lane >> 2;
    const int lc = (lane & 3) * 8;

    f32x4 acc[4][4];
    const f32x4 z4 = {0.f,0.f,0.f,0.f};
#pragma unroll
    for (int s = 0; s < 4; ++s)
#pragma unroll
        for (int j = 0; j < 4; ++j) acc[s][j] = z4;

#pragma unroll 1
    for (int k0 = 0; k0 < D_MODEL; k0 += 32) {
        __syncthreads();
#pragma unroll
        for (int cc = 0; cc < 2; ++cc) {
            const int c  = w*2 + cc;
            const int gr = c*16 + lr;
            gload_lds16(&Ah [(size_t)(m0 + gr)*D_MODEL + k0 + lc], &sAh[c*512]);
            gload_lds16(&Bh_[(size_t)(n0 + gr)*D_MODEL + k0 + lc], &sBh[c*512]);
        }
        __syncthreads();

        bf16x8 a_h[4];
#pragma unroll
        for (int s = 0; s < 4; ++s)
            a_h[s] = *(const bf16x8*)&sAh[(wr + s*16 + ln)*32 + quad*8];
#pragma unroll
        for (int j0 = 0; j0 < 4; ++j0) {
            bf16x8 b_h = *(const bf16x8*)&sBh[(wc + j0*16 + ln)*32 + quad*8];
#pragma unroll
            for (int s = 0; s < 4; ++s)
                acc[s][j0] = mfma16(a_h[s], b_h, acc[s][j0]);
        }
    }

#pragma unroll
    for (int s = 0; s < 4; ++s) {
#pragma unroll
        for (int j0 = 0; j0 < 4; ++j0) {
            const int dfull = n0 + wc + j0*16 + ln;
            const float bia = bias[dfull];
#pragma unroll
            for (int i = 0; i < 4; ++i) {
                int m = m0 + wr + s*16 + quad*4 + i;
                C[(size_t)m*D_MODEL + dfull] = acc[s][j0][i] + bia;
            }
        }
    }
}

// ---------------------------------------------------------------------------
// MFMA flash attention — R14/R17 verified version (absmax 0.98e-3 attn path;
// e2e absmax 0.001953125).  4 waves, V double-buffered, K single-buffered
// with lgkm release barrier, T5 setprio.  R18's single-buffer-V variant
// failed its correctness control (suspected rule-#18-class reordering of the
// V register reads across the release barrier) and is abandoned.
// ---------------------------------------------------------------------------
#define LPP 72

__global__ __launch_bounds__(256, 3)
void attn_mfma(const u16* __restrict__ Qh,
               const u16* __restrict__ Kh,
               const u16* __restrict__ Vh, u16* __restrict__ Obh)
{
    __shared__ __align__(16) u16 sK [4096];   // j0*1024 + half*512
    __shared__ __align__(16) u16 sV0[4096];   // d0*1024 + half*512
    __shared__ __align__(16) u16 sV1[4096];
    __shared__ __align__(16) u16 sP [128*LPP];

    const int tid  = threadIdx.x;
    const int w    = tid >> 6;
    const int lane = tid & 63;
    const int ln   = lane & 15;
    const int quad = lane >> 4;
    const int bh   = blockIdx.y;
    const int b_   = bh / NUM_HEADS;
    const int h    = bh % NUM_HEADS;
    const int q0   = blockIdx.x * 128;
    const int wq   = w * 32;
    const int lofs = lane * 8;        // this lane's 16 B frag within a 1 KiB chunk

    const size_t bhL = (size_t)bh * SEQ;
    const u16* __restrict__ Kbh = Kh + bhL * D_K;                 // [key][dk]
    const u16* __restrict__ Vb  = Vh + (size_t)bh * D_K * SEQ;    // [dk][key']

    // Q fragments (A-layout: m=ln, k=quad*8+j)
    bf16x8 qh[2][2];
#pragma unroll
    for (int s = 0; s < 2; ++s) {
        const size_t row = bhL + q0 + wq + s*16 + ln;
        const u16* qph = Qh + row * D_K;
        qh[s][0] = *(const bf16x8*)&qph[quad*8];
        qh[s][1] = *(const bf16x8*)&qph[32 + quad*8];
    }

    const bf16x8 ones = {(short)0x3F80,(short)0x3F80,(short)0x3F80,(short)0x3F80,
                         (short)0x3F80,(short)0x3F80,(short)0x3F80,(short)0x3F80};
    const f32x4 z4 = {0.f,0.f,0.f,0.f};
    f32x4 lacc[2] = {z4, z4};
    f32x4 o[2][4];
#pragma unroll
    for (int s = 0; s < 2; ++s)
#pragma unroll
        for (int d0 = 0; d0 < 4; ++d0) o[s][d0] = z4;

    // ---- prologue: DMA tile 0 (wave w stages K j0=w and V d0=w) ----
    gload_lds16(Vb + (size_t)(w*16 + ln)*SEQ + quad*8,      &sV0[w*1024]);
    gload_lds16(Vb + (size_t)(w*16 + ln)*SEQ + 32 + quad*8, &sV0[w*1024 + 512]);
#pragma unroll
    for (int t = 0; t < 2; ++t) {
        gload_lds16(Kbh + (size_t)(w*16 + ln)*D_K + t*32 + quad*8,
                    &sK[w*1024 + t*512]);
    }

#define ATTN_BODY(SVC, SVN, KTN)                                               \
    {                                                                          \
        __syncthreads();  /* drains vmcnt: this tile's K+V DMAs visible */     \
        /* V prefetch for next tile (other buffer: released by the barrier) */ \
        gload_lds16(Vb + (size_t)(w*16 + ln)*SEQ + (KTN) + quad*8,             \
                    &SVN[w*1024]);                                             \
        gload_lds16(Vb + (size_t)(w*16 + ln)*SEQ + (KTN) + 32 + quad*8,        \
                    &SVN[w*1024 + 512]);                                       \
        /* S = Q K^T : Q plain, K plain (2 mfma per s,j0) */                   \
        f32x4 S[2][4];                                                         \
        __builtin_amdgcn_s_setprio(1);                                         \
        _Pragma("unroll")                                                      \
        for (int j0 = 0; j0 < 4; ++j0) {                                       \
            bf16x8 kh0 = *(const bf16x8*)&sK[j0*1024       + lofs];            \
            bf16x8 kh1 = *(const bf16x8*)&sK[j0*1024 + 512 + lofs];            \
            _Pragma("unroll")                                                  \
            for (int s = 0; s < 2; ++s) {                                      \
                f32x4 a = z4;                                                  \
                a = mfma16(qh[s][0], kh0, a);                                  \
                a = mfma16(qh[s][1], kh1, a);                                  \
                S[s][j0] = a;                                                  \
            }                                                                  \
        }                                                                      \
        __builtin_amdgcn_s_setprio(0);                                         \
        /* all waves' K reads retired -> release sK, prefetch next K tile */   \
        asm volatile("s_waitcnt lgkmcnt(0)\n\ts_barrier" ::: "memory");        \
        _Pragma("unroll")                                                      \
        for (int t = 0; t < 2; ++t) {                                          \
            gload_lds16(Kbh + (size_t)((KTN) + w*16 + ln)*D_K + t*32 + quad*8, \
                        &sK[w*1024 + t*512]);                                  \
        }                                                                      \
        /* P = exp2(S); trunc-pack via v_perm into wave-private sP */          \
        _Pragma("unroll")                                                      \
        for (int s = 0; s < 2; ++s) {                                          \
            _Pragma("unroll")                                                  \
            for (int i = 0; i < 4; ++i) {                                      \
                u32 u0 = __float_as_uint(fast_exp2(S[s][0][i]));               \
                u32 u1 = __float_as_uint(fast_exp2(S[s][1][i]));               \
                u32 u2 = __float_as_uint(fast_exp2(S[s][2][i]));               \
                u32 u3 = __float_as_uint(fast_exp2(S[s][3][i]));               \
                uint2 pk;                                                      \
                pk.x = __builtin_amdgcn_perm(u1, u0, 0x07060302u);             \
                pk.y = __builtin_amdgcn_perm(u3, u2, 0x07060302u);             \
                int prow = wq + s*16 + quad*4 + i;                             \
                *(uint2*)&sP[prow*LPP + ln*4] = pk;                            \
            }                                                                  \
        }                                                                      \
        /* O += P V ; l += P @ ones  (sP wave-private: no barrier) */          \
        bf16x8 pa[2][2];                                                       \
        _Pragma("unroll")                                                      \
        for (int s = 0; s < 2; ++s) {                                          \
            const u16* pp = &sP[(wq + s*16 + ln)*LPP];                         \
            pa[s][0] = *(const bf16x8*)&pp[quad*8];                            \
            pa[s][1] = *(const bf16x8*)&pp[32 + quad*8];                       \
        }                                                                      \
        __builtin_amdgcn_s_setprio(1);                                         \
        _Pragma("unroll")                                                      \
        for (int s = 0; s < 2; ++s) {                                          \
            lacc[s] = mfma16(pa[s][0], ones, lacc[s]);                         \
            lacc[s] = mfma16(pa[s][1], ones, lacc[s]);                         \
        }                                                                      \
        _Pragma("unroll")                                                      \
        for (int d0 = 0; d0 < 4; ++d0) {                                       \
            bf16x8 vh0 = *(const bf16x8*)&SVC[d0*1024       + lofs];           \
            bf16x8 vh1 = *(const bf16x8*)&SVC[d0*1024 + 512 + lofs];           \
            _Pragma("unroll")                                                  \
            for (int s = 0; s < 2; ++s) {                                      \
                f32x4 a = o[s][d0];                                            \
                a = mfma16(pa[s][0], vh0, a);                                  \
                a = mfma16(pa[s][1], vh1, a);                                  \
                o[s][d0] = a;                                                  \
            }                                                                  \
        }                                                                      \
        __builtin_amdgcn_s_setprio(0);                                         \
    }

#pragma unroll 1
    for (int kt = 0; kt < SEQ; kt += 128) {
        const int kn1 = kt + 64;
        const int kn2 = (kt + 128 == SEQ) ? 0 : kt + 128;   // wrap: harmless
        ATTN_BODY(sV0, sV1, kn1)
        ATTN_BODY(sV1, sV0, kn2)
    }
#undef ATTN_BODY

    // ---- epilogue: l row-sums already in lacc (all lanes); store bf16 ----
#pragma unroll
    for (int s = 0; s < 2; ++s) {
        float inv[4];
#pragma unroll
        for (int i = 0; i < 4; ++i) inv[i] = 1.0f / lacc[s][i];
#pragma unroll
        for (int d0 = 0; d0 < 4; ++d0) {
#pragma unroll
            for (int i = 0; i < 4; ++i) {
                int q = q0 + wq + s*16 + quad*4 + i;
                Obh[((size_t)b_*SEQ + q)*D_MODEL + h*D_K + d0*16 + ln] =
                    f2bf(o[s][d0][i] * inv[i]);
            }
        }
    }
}

extern "C" void kernel_launch(void* const* d_in, const int* in_sizes, int n_in,
                              void* d_out, int out_size, void* d_ws, size_t ws_size,
                              hipStream_t stream)
{
    const float* x  = (const float*)d_in[0];
    const float* Wq = (const float*)d_in[1];
    const float* bq = (const float*)d_in[2];
    const float* Wk = (const float*)d_in[3];
    const float* bk = (const float*)d_in[4];
    const float* Wv = (const float*)d_in[5];
    const float* bv = (const float*)d_in[6];
    const float* Wo = (const float*)d_in[7];
    const float* bo = (const float*)d_in[8];
    float* out = (float*)d_out;

    const size_t nX = (size_t)MROWS * D_MODEL;    // 6291456
    const size_t nW = (size_t)D_MODEL * D_MODEL;  // 589824

    u16* Xh  = (u16*)d_ws;
    u16* Wqh = Xh  + nX;
    u16* Wkh = Wqh + nW;
    u16* Wvh = Wkh + nW;
    u16* Woh = Wvh + nW;
    u16* Qh  = Woh + nW;
    u16* Kh  = Qh  + nX;
    u16* Vh  = Kh  + nX;
    u16* Obh = Xh;                 // alias: Xh dead after proj_gemm

    dim3 blk(256);
    convert_all<<<dim3(XBLKS + 4*WBLKS), blk, 0, stream>>>(
        x, Wq, Wk, Wv, Wo, Xh, Wqh, Wkh, Wvh, Woh);
    proj_gemm<<<dim3(MROWS/128, D_MODEL/128, 3), blk, 0, stream>>>(
        Xh, Wqh, Wkh, Wvh, bq, bk, bv, Qh, Kh, Vh);
    attn_mfma<<<dim3(SEQ/128, BH_), blk, 0, stream>>>(Qh, Kh, Vh, Obh);
    out_gemm<<<dim3(MROWS/128, D_MODEL/128), blk, 0, stream>>>(Obh, Woh, bo, out);
}